// Round 1
// baseline (641.638 us; speedup 1.0000x reference)
//
#include <hip/hip_runtime.h>
#include <hip/hip_bf16.h>

// RPL_Asymm_3d_spconv: 3x (3-tap gathered GEMM -> BN(train) -> sigmoid), then (s1+s2+s3)*features
// N=131072, C=256. bf16 MFMA path (no fp32 MFMA on CDNA4).
//
// ws layout (~135.4 MiB):
//   fb   : (N+1)*256 bf16  (row N = zeros, sentinel pad)   67,109,376 B
//   wbT  : 9*256*256 bf16  ([axis*3+tap][cout][cin])        1,179,648 B
//   stats: 3*2*256 f32 (sum, sumsq per axis)                    6,144 B
//   ss   : 3*2*256 f32 (scale, shift per axis)                  6,144 B
//   hbuf : N*256 bf16 (per-axis conv output, reused)        67,108,864 B

#define NP 131072
#define CC 256

typedef __attribute__((ext_vector_type(4))) float f32x4;
typedef __attribute__((ext_vector_type(8))) short bf16x8;

__device__ __forceinline__ unsigned short f2bf(float f) {
    unsigned int u = __float_as_uint(f);
    u += 0x7FFFu + ((u >> 16) & 1u);   // RNE
    return (unsigned short)(u >> 16);
}
__device__ __forceinline__ float bf2f(unsigned short s) {
    return __uint_as_float(((unsigned int)s) << 16);
}

__device__ __forceinline__ void gload_lds16(const void* g, void* l) {
    __builtin_amdgcn_global_load_lds(
        (const __attribute__((address_space(1))) unsigned int*)g,
        (__attribute__((address_space(3))) unsigned int*)l, 16, 0, 0);
}

__global__ void zero_stats_k(float* stats) {
    int i = blockIdx.x * 256 + threadIdx.x;
    if (i < 3 * 2 * CC) stats[i] = 0.f;
}

__global__ void cast_features_k(const float* __restrict__ f, unsigned short* __restrict__ fb) {
    size_t e = ((size_t)blockIdx.x * 256 + threadIdx.x) * 8;
    const size_t tot = (size_t)(NP + 1) * CC;
    if (e >= tot) return;
    unsigned short tmp[8];
    if (e >= (size_t)NP * CC) {
        #pragma unroll
        for (int j = 0; j < 8; ++j) tmp[j] = 0;  // pad row
    } else {
        float4 v0 = *(const float4*)(f + e);
        float4 v1 = *(const float4*)(f + e + 4);
        tmp[0] = f2bf(v0.x); tmp[1] = f2bf(v0.y); tmp[2] = f2bf(v0.z); tmp[3] = f2bf(v0.w);
        tmp[4] = f2bf(v1.x); tmp[5] = f2bf(v1.y); tmp[6] = f2bf(v1.z); tmp[7] = f2bf(v1.w);
    }
    *(bf16x8*)(fb + e) = *(bf16x8*)tmp;
}

// wbT[m][cout][cin] = W_m[tap][cin][cout], m = axis*3+tap
__global__ void cast_weights_k(const float* __restrict__ W1, const float* __restrict__ W2,
                               const float* __restrict__ W3, unsigned short* __restrict__ wbT) {
    int bid  = blockIdx.x;        // 0..2303
    int m    = bid >> 8;          // 0..8
    int cout = bid & 255;
    int cin  = threadIdx.x;
    const float* W = (m < 3) ? W1 : (m < 6) ? W2 : W3;
    int tap = m - (m / 3) * 3;
    float v = W[((size_t)tap * CC + cin) * CC + cout];
    wbT[((size_t)m * CC + cout) * CC + cin] = f2bf(v);
}

// h[N][256] = sum_tap gather(fb, nbr[:,tap]) @ W[tap]
// 128x128 tile, 4 waves, BK=32, global_load_lds staging, mfma 16x16x32 bf16
__global__ __launch_bounds__(256)
void gemm_conv_k(const unsigned short* __restrict__ fb, const unsigned short* __restrict__ wT,
                 const int* __restrict__ nbr, unsigned short* __restrict__ h) {
    __shared__ unsigned short As[128 * 32];
    __shared__ unsigned short Bs[128 * 32];
    __shared__ int rowIdx[3 * 128];

    const int tid     = threadIdx.x;
    const int lane    = tid & 63;
    const int wave    = tid >> 6;
    const int colBase = blockIdx.x * 128;
    const int rowBase = blockIdx.y * 128;

    if (tid < 128) {
        int i = rowBase + tid;
        rowIdx[tid]       = nbr[(size_t)i * 3 + 0];
        rowIdx[128 + tid] = nbr[(size_t)i * 3 + 1];
        rowIdx[256 + tid] = nbr[(size_t)i * 3 + 2];
    }

    f32x4 acc[4][4] = {};

    const int wr     = wave >> 1;
    const int wc     = wave & 1;
    const int fr     = lane & 15;
    const int fkB    = (lane >> 4) * 8;   // frag k offset (elements)
    const int sSub   = lane >> 2;         // 0..15 row within 16-row staging group
    const int sChunk = lane & 3;          // 16B chunk within 64B row

    __syncthreads();

    for (int tap = 0; tap < 3; ++tap) {
        const unsigned short* wTt = wT + (size_t)tap * CC * CC;
        const int* rIdx = rowIdx + tap * 128;
        for (int kk = 0; kk < CC; kk += 32) {
            // stage A (gathered rows) and B, 16B/lane via global_load_lds
            #pragma unroll
            for (int u = 0; u < 2; ++u) {
                int q  = wave * 2 + u;               // 0..7, covers rows q*16..q*16+15
                int ar = rIdx[q * 16 + sSub];        // sentinel NP -> zero pad row
                const unsigned short* asrc = fb + ((size_t)ar * CC + kk + sChunk * 8);
                gload_lds16(asrc, As + q * 512);
                int bc = colBase + q * 16 + sSub;
                const unsigned short* bsrc = wTt + ((size_t)bc * CC + kk + sChunk * 8);
                gload_lds16(bsrc, Bs + q * 512);
            }
            __syncthreads();

            bf16x8 aF[4], bF[4];
            #pragma unroll
            for (int m = 0; m < 4; ++m)
                aF[m] = *(const bf16x8*)(As + (wr * 64 + m * 16 + fr) * 32 + fkB);
            #pragma unroll
            for (int n = 0; n < 4; ++n)
                bF[n] = *(const bf16x8*)(Bs + (wc * 64 + n * 16 + fr) * 32 + fkB);
            #pragma unroll
            for (int m = 0; m < 4; ++m)
                #pragma unroll
                for (int n = 0; n < 4; ++n)
                    acc[m][n] = __builtin_amdgcn_mfma_f32_16x16x32_bf16(aF[m], bF[n], acc[m][n], 0, 0, 0);
            __syncthreads();
        }
    }

    // epilogue: C/D layout col=lane&15, row=(lane>>4)*4+reg (measured m89/m91)
    const int orow = (lane >> 4) * 4;
    #pragma unroll
    for (int m = 0; m < 4; ++m) {
        #pragma unroll
        for (int n = 0; n < 4; ++n) {
            int col = colBase + wc * 64 + n * 16 + fr;
            int row = rowBase + wr * 64 + m * 16 + orow;
            #pragma unroll
            for (int j = 0; j < 4; ++j)
                h[(size_t)(row + j) * CC + col] = f2bf(acc[m][n][j]);
        }
    }
}

__global__ void stats_k(const unsigned short* __restrict__ h, float* __restrict__ stats) {
    int c = threadIdx.x;
    float s = 0.f, s2 = 0.f;
    for (int i = blockIdx.x; i < NP; i += 512) {
        float v = bf2f(h[(size_t)i * CC + c]);
        s += v; s2 += v * v;
    }
    atomicAdd(&stats[c], s);
    atomicAdd(&stats[CC + c], s2);
}

__global__ void finalize_k(const float* __restrict__ stats, const float* __restrict__ g,
                           const float* __restrict__ b, float* __restrict__ ss) {
    int c = threadIdx.x;
    float mu  = stats[c] * (1.f / NP);
    float var = stats[CC + c] * (1.f / NP) - mu * mu;
    float sc  = g[c] * rsqrtf(var + 1e-5f);
    ss[c]      = sc;
    ss[CC + c] = b[c] - mu * sc;
}

// mode 0: out = s ; mode 1: out += s ; mode 2: out = (out + s) * feat
__global__ void apply_k(const unsigned short* __restrict__ h, const float* __restrict__ ss,
                        const float* __restrict__ feat, float* __restrict__ out, const int mode) {
    size_t e = ((size_t)blockIdx.x * 256 + threadIdx.x) * 8;
    int c0 = (int)(e & (CC - 1));
    bf16x8 hv = *(const bf16x8*)(h + e);
    float s[8];
    #pragma unroll
    for (int j = 0; j < 8; ++j) {
        float x = bf2f((unsigned short)hv[j]);
        float z = ss[c0 + j] * x + ss[CC + c0 + j];
        s[j] = 1.f / (1.f + __expf(-z));
    }
    float4* o = (float4*)(out + e);
    if (mode == 0) {
        o[0] = make_float4(s[0], s[1], s[2], s[3]);
        o[1] = make_float4(s[4], s[5], s[6], s[7]);
    } else if (mode == 1) {
        float4 a0 = o[0], a1 = o[1];
        o[0] = make_float4(a0.x + s[0], a0.y + s[1], a0.z + s[2], a0.w + s[3]);
        o[1] = make_float4(a1.x + s[4], a1.y + s[5], a1.z + s[6], a1.w + s[7]);
    } else {
        float4 a0 = o[0], a1 = o[1];
        const float4* fv = (const float4*)(feat + e);
        float4 f0 = fv[0], f1 = fv[1];
        o[0] = make_float4((a0.x + s[0]) * f0.x, (a0.y + s[1]) * f0.y,
                           (a0.z + s[2]) * f0.z, (a0.w + s[3]) * f0.w);
        o[1] = make_float4((a1.x + s[4]) * f1.x, (a1.y + s[5]) * f1.y,
                           (a1.z + s[6]) * f1.z, (a1.w + s[7]) * f1.w);
    }
}

extern "C" void kernel_launch(void* const* d_in, const int* in_sizes, int n_in,
                              void* d_out, int out_size, void* d_ws, size_t ws_size,
                              hipStream_t stream) {
    const float* feat = (const float*)d_in[0];
    const float* W1   = (const float*)d_in[1];
    const float* W2   = (const float*)d_in[2];
    const float* W3   = (const float*)d_in[3];
    const float* g1   = (const float*)d_in[4];
    const float* b1   = (const float*)d_in[5];
    const float* g2   = (const float*)d_in[6];
    const float* b2   = (const float*)d_in[7];
    const float* g3   = (const float*)d_in[8];
    const float* b3   = (const float*)d_in[9];
    const int* nbr1   = (const int*)d_in[10];
    const int* nbr2   = (const int*)d_in[11];
    const int* nbr3   = (const int*)d_in[12];
    float* out = (float*)d_out;

    char* w = (char*)d_ws;
    unsigned short* fb  = (unsigned short*)w;  w += (size_t)(NP + 1) * CC * 2;
    unsigned short* wbT = (unsigned short*)w;  w += (size_t)9 * CC * CC * 2;
    float* stats        = (float*)w;           w += (size_t)3 * 2 * CC * 4;
    float* ss           = (float*)w;           w += (size_t)3 * 2 * CC * 4;
    unsigned short* hbuf = (unsigned short*)w;

    zero_stats_k<<<6, 256, 0, stream>>>(stats);
    {
        size_t tot = (size_t)(NP + 1) * CC / 8;
        int blocks = (int)((tot + 255) / 256);
        cast_features_k<<<blocks, 256, 0, stream>>>(feat, fb);
    }
    cast_weights_k<<<2304, 256, 0, stream>>>(W1, W2, W3, wbT);

    const int* nbrs[3]  = {nbr1, nbr2, nbr3};
    const float* gs[3]  = {g1, g2, g3};
    const float* bs[3]  = {b1, b2, b3};
    for (int a = 0; a < 3; ++a) {
        gemm_conv_k<<<dim3(2, 1024), 256, 0, stream>>>(fb, wbT + (size_t)a * 3 * CC * CC,
                                                       nbrs[a], hbuf);
        stats_k<<<512, 256, 0, stream>>>(hbuf, stats + a * 2 * CC);
        finalize_k<<<1, 256, 0, stream>>>(stats + a * 2 * CC, gs[a], bs[a], ss + a * 2 * CC);
        apply_k<<<16384, 256, 0, stream>>>(hbuf, ss + a * 2 * CC, feat, out, a);
    }
}

// Round 2
// 321.825 us; speedup vs baseline: 1.9937x; 1.9937x over previous
//
#include <hip/hip_runtime.h>
#include <hip/hip_bf16.h>

// RPL_Asymm_3d_spconv: 3x (3-tap gathered GEMM -> BN(train) -> sigmoid), then (s1+s2+s3)*features
// N=131072, C=256. bf16 MFMA path (no fp32 MFMA on CDNA4).
//
// Round 2: stats fused into GEMM epilogue; 3 axes in one dispatch (grid.z=3);
// single final apply pass; LDS chunk-XOR swizzle (source-side) to kill the
// 4-cycle/ds_read_b128 half-wave bank conflict.
//
// ws layout (~270 MiB of 512 MiB):
//   fb   : (N+1)*256 bf16  (row N = zeros, sentinel pad)   67,109,376 B
//   wbT  : 9*256*256 bf16  ([axis*3+tap][cout][cin])        1,179,648 B
//   stats: 3*2*256 f32 (sum, sumsq per axis)                    6,144 B
//   ss   : 3*2*256 f32 (scale, shift per axis)                  6,144 B
//   hbuf : 3*N*256 bf16 (per-axis conv outputs)            201,326,592 B

#define NP 131072
#define CC 256

typedef __attribute__((ext_vector_type(4))) float f32x4;
typedef __attribute__((ext_vector_type(8))) short bf16x8;

__device__ __forceinline__ unsigned short f2bf(float f) {
    unsigned int u = __float_as_uint(f);
    u += 0x7FFFu + ((u >> 16) & 1u);   // RNE
    return (unsigned short)(u >> 16);
}
__device__ __forceinline__ float bf2f(unsigned short s) {
    return __uint_as_float(((unsigned int)s) << 16);
}

__device__ __forceinline__ void gload_lds16(const void* g, void* l) {
    __builtin_amdgcn_global_load_lds(
        (const __attribute__((address_space(1))) unsigned int*)g,
        (__attribute__((address_space(3))) unsigned int*)l, 16, 0, 0);
}

__global__ void zero_stats_k(float* stats) {
    int i = blockIdx.x * 256 + threadIdx.x;
    if (i < 3 * 2 * CC) stats[i] = 0.f;
}

__global__ void cast_features_k(const float* __restrict__ f, unsigned short* __restrict__ fb) {
    size_t e = ((size_t)blockIdx.x * 256 + threadIdx.x) * 8;
    const size_t tot = (size_t)(NP + 1) * CC;
    if (e >= tot) return;
    unsigned short tmp[8];
    if (e >= (size_t)NP * CC) {
        #pragma unroll
        for (int j = 0; j < 8; ++j) tmp[j] = 0;  // pad row
    } else {
        float4 v0 = *(const float4*)(f + e);
        float4 v1 = *(const float4*)(f + e + 4);
        tmp[0] = f2bf(v0.x); tmp[1] = f2bf(v0.y); tmp[2] = f2bf(v0.z); tmp[3] = f2bf(v0.w);
        tmp[4] = f2bf(v1.x); tmp[5] = f2bf(v1.y); tmp[6] = f2bf(v1.z); tmp[7] = f2bf(v1.w);
    }
    *(bf16x8*)(fb + e) = *(bf16x8*)tmp;
}

// wbT[m][cout][cin] = W_m[tap][cin][cout], m = axis*3+tap
__global__ void cast_weights_k(const float* __restrict__ W1, const float* __restrict__ W2,
                               const float* __restrict__ W3, unsigned short* __restrict__ wbT) {
    int bid  = blockIdx.x;        // 0..2303
    int m    = bid >> 8;          // 0..8
    int cout = bid & 255;
    int cin  = threadIdx.x;
    const float* W = (m < 3) ? W1 : (m < 6) ? W2 : W3;
    int tap = m - (m / 3) * 3;
    float v = W[((size_t)tap * CC + cin) * CC + cout];
    wbT[((size_t)m * CC + cout) * CC + cin] = f2bf(v);
}

// h[axis][N][256] = sum_tap gather(fb, nbr_axis[:,tap]) @ W_axis[tap]
// 128x128 tile, 4 waves, BK=32, global_load_lds staging (source-side chunk
// swizzle), mfma 16x16x32 bf16. BN sum/sumsq fused into epilogue.
__global__ __launch_bounds__(256)
void gemm_conv_fused_k(const unsigned short* __restrict__ fb,
                       const unsigned short* __restrict__ wbT,
                       const int* __restrict__ nbr1, const int* __restrict__ nbr2,
                       const int* __restrict__ nbr3,
                       unsigned short* __restrict__ hbase,
                       float* __restrict__ statsBase) {
    __shared__ unsigned short As[128 * 32];
    __shared__ unsigned short Bs[128 * 32];
    __shared__ int rowIdx[3 * 128];
    __shared__ float colsum[128];
    __shared__ float colsq[128];

    const int axis = blockIdx.z;
    const int* nbr = (axis == 0) ? nbr1 : (axis == 1) ? nbr2 : nbr3;
    const unsigned short* wT = wbT + (size_t)axis * 3 * CC * CC;
    unsigned short* h = hbase + (size_t)axis * NP * CC;
    float* stats = statsBase + axis * 2 * CC;

    const int tid     = threadIdx.x;
    const int lane    = tid & 63;
    const int wave    = tid >> 6;
    const int colBase = blockIdx.x * 128;
    const int rowBase = blockIdx.y * 128;

    if (tid < 128) {
        int i = rowBase + tid;
        rowIdx[tid]       = nbr[(size_t)i * 3 + 0];
        rowIdx[128 + tid] = nbr[(size_t)i * 3 + 1];
        rowIdx[256 + tid] = nbr[(size_t)i * 3 + 2];
        colsum[tid] = 0.f;
        colsq[tid]  = 0.f;
    }

    f32x4 acc[4][4] = {};

    const int wr     = wave >> 1;
    const int wc     = wave & 1;
    const int fr     = lane & 15;
    const int sSub   = lane >> 2;         // 0..15 row within 16-row staging group
    const int sChunk = lane & 3;          // 16B chunk slot within 64B row (LDS, linear)
    // source-side swizzle: LDS[row][p] holds global chunk p ^ ((row>>1)&3)
    const int gChunk = sChunk ^ ((sSub >> 1) & 3);   // global chunk this lane fetches
    // fragment read: global chunk (lane>>4) of row r sits at p = (lane>>4) ^ ((r>>1)&3)
    const int rChunkOff = ((lane >> 4) ^ ((fr >> 1) & 3)) * 8;  // elements

    __syncthreads();

    for (int tap = 0; tap < 3; ++tap) {
        const unsigned short* wTt = wT + (size_t)tap * CC * CC;
        const int* rIdx = rowIdx + tap * 128;
        for (int kk = 0; kk < CC; kk += 32) {
            #pragma unroll
            for (int u = 0; u < 2; ++u) {
                int q  = wave * 2 + u;               // 16-row staging group
                int ar = rIdx[q * 16 + sSub];        // sentinel NP -> zero pad row
                const unsigned short* asrc = fb + ((size_t)ar * CC + kk + gChunk * 8);
                gload_lds16(asrc, As + q * 512);
                int bc = colBase + q * 16 + sSub;
                const unsigned short* bsrc = wTt + ((size_t)bc * CC + kk + gChunk * 8);
                gload_lds16(bsrc, Bs + q * 512);
            }
            __syncthreads();

            bf16x8 aF[4], bF[4];
            #pragma unroll
            for (int m = 0; m < 4; ++m)
                aF[m] = *(const bf16x8*)(As + (wr * 64 + m * 16 + fr) * 32 + rChunkOff);
            #pragma unroll
            for (int n = 0; n < 4; ++n)
                bF[n] = *(const bf16x8*)(Bs + (wc * 64 + n * 16 + fr) * 32 + rChunkOff);
            #pragma unroll
            for (int m = 0; m < 4; ++m)
                #pragma unroll
                for (int n = 0; n < 4; ++n)
                    acc[m][n] = __builtin_amdgcn_mfma_f32_16x16x32_bf16(aF[m], bF[n], acc[m][n], 0, 0, 0);
            __syncthreads();
        }
    }

    // epilogue: C/D layout col=lane&15, row=(lane>>4)*4+reg (measured m89/m91)
    // store bf16 h + accumulate per-column sum/sumsq of the ROUNDED values
    const int orow = (lane >> 4) * 4;
    float psum[4], psq[4];
    #pragma unroll
    for (int n = 0; n < 4; ++n) { psum[n] = 0.f; psq[n] = 0.f; }
    #pragma unroll
    for (int m = 0; m < 4; ++m) {
        #pragma unroll
        for (int n = 0; n < 4; ++n) {
            int col = colBase + wc * 64 + n * 16 + fr;
            int row = rowBase + wr * 64 + m * 16 + orow;
            #pragma unroll
            for (int j = 0; j < 4; ++j) {
                unsigned short hb = f2bf(acc[m][n][j]);
                float v = bf2f(hb);
                h[(size_t)(row + j) * CC + col] = hb;
                psum[n] += v;
                psq[n]  += v * v;
            }
        }
    }
    // threads sharing a column differ only in lane bits 4,5 -> shfl reduce
    #pragma unroll
    for (int n = 0; n < 4; ++n) {
        psum[n] += __shfl_xor(psum[n], 16);
        psum[n] += __shfl_xor(psum[n], 32);
        psq[n]  += __shfl_xor(psq[n], 16);
        psq[n]  += __shfl_xor(psq[n], 32);
    }
    if ((lane >> 4) == 0) {
        #pragma unroll
        for (int n = 0; n < 4; ++n) {
            int cl = wc * 64 + n * 16 + fr;
            atomicAdd(&colsum[cl], psum[n]);
            atomicAdd(&colsq[cl],  psq[n]);
        }
    }
    __syncthreads();
    if (tid < 128) {
        int c = colBase + tid;
        atomicAdd(&stats[c],      colsum[tid]);
        atomicAdd(&stats[CC + c], colsq[tid]);
    }
}

__global__ void finalize3_k(const float* __restrict__ stats,
                            const float* __restrict__ g1, const float* __restrict__ b1,
                            const float* __restrict__ g2, const float* __restrict__ b2,
                            const float* __restrict__ g3, const float* __restrict__ b3,
                            float* __restrict__ ss) {
    int a = blockIdx.x;
    int c = threadIdx.x;
    const float* g = (a == 0) ? g1 : (a == 1) ? g2 : g3;
    const float* b = (a == 0) ? b1 : (a == 1) ? b2 : b3;
    const float* st = stats + a * 2 * CC;
    float* s = ss + a * 2 * CC;
    float mu  = st[c] * (1.f / NP);
    float var = st[CC + c] * (1.f / NP) - mu * mu;
    float sc  = g[c] * rsqrtf(var + 1e-5f);
    s[c]      = sc;
    s[CC + c] = b[c] - mu * sc;
}

// out = (sigmoid(a1*h1+c1) + sigmoid(a2*h2+c2) + sigmoid(a3*h3+c3)) * feat
__global__ void apply3_k(const unsigned short* __restrict__ h1,
                         const unsigned short* __restrict__ h2,
                         const unsigned short* __restrict__ h3,
                         const float* __restrict__ ss,
                         const float* __restrict__ feat, float* __restrict__ out) {
    size_t e = ((size_t)blockIdx.x * 256 + threadIdx.x) * 8;
    int c0 = (int)(e & (CC - 1));
    bf16x8 v1 = *(const bf16x8*)(h1 + e);
    bf16x8 v2 = *(const bf16x8*)(h2 + e);
    bf16x8 v3 = *(const bf16x8*)(h3 + e);
    float s[8];
    #pragma unroll
    for (int j = 0; j < 8; ++j) {
        float z1 = ss[c0 + j]            * bf2f((unsigned short)v1[j]) + ss[CC + c0 + j];
        float z2 = ss[2 * CC + c0 + j]   * bf2f((unsigned short)v2[j]) + ss[3 * CC + c0 + j];
        float z3 = ss[4 * CC + c0 + j]   * bf2f((unsigned short)v3[j]) + ss[5 * CC + c0 + j];
        s[j] = 1.f / (1.f + __expf(-z1)) + 1.f / (1.f + __expf(-z2)) + 1.f / (1.f + __expf(-z3));
    }
    const float4* fv = (const float4*)(feat + e);
    float4 f0 = fv[0], f1 = fv[1];
    float4* o = (float4*)(out + e);
    o[0] = make_float4(s[0] * f0.x, s[1] * f0.y, s[2] * f0.z, s[3] * f0.w);
    o[1] = make_float4(s[4] * f1.x, s[5] * f1.y, s[6] * f1.z, s[7] * f1.w);
}

extern "C" void kernel_launch(void* const* d_in, const int* in_sizes, int n_in,
                              void* d_out, int out_size, void* d_ws, size_t ws_size,
                              hipStream_t stream) {
    const float* feat = (const float*)d_in[0];
    const float* W1   = (const float*)d_in[1];
    const float* W2   = (const float*)d_in[2];
    const float* W3   = (const float*)d_in[3];
    const float* g1   = (const float*)d_in[4];
    const float* b1   = (const float*)d_in[5];
    const float* g2   = (const float*)d_in[6];
    const float* b2   = (const float*)d_in[7];
    const float* g3   = (const float*)d_in[8];
    const float* b3   = (const float*)d_in[9];
    const int* nbr1   = (const int*)d_in[10];
    const int* nbr2   = (const int*)d_in[11];
    const int* nbr3   = (const int*)d_in[12];
    float* out = (float*)d_out;

    char* w = (char*)d_ws;
    unsigned short* fb   = (unsigned short*)w;  w += (size_t)(NP + 1) * CC * 2;
    unsigned short* wbT  = (unsigned short*)w;  w += (size_t)9 * CC * CC * 2;
    float* stats         = (float*)w;           w += (size_t)3 * 2 * CC * 4;
    float* ss            = (float*)w;           w += (size_t)3 * 2 * CC * 4;
    unsigned short* hbuf = (unsigned short*)w;  // 3 * N * C bf16

    zero_stats_k<<<6, 256, 0, stream>>>(stats);
    {
        size_t tot = (size_t)(NP + 1) * CC / 8;
        int blocks = (int)((tot + 255) / 256);
        cast_features_k<<<blocks, 256, 0, stream>>>(feat, fb);
    }
    cast_weights_k<<<2304, 256, 0, stream>>>(W1, W2, W3, wbT);

    gemm_conv_fused_k<<<dim3(2, 1024, 3), 256, 0, stream>>>(fb, wbT, nbr1, nbr2, nbr3,
                                                            hbuf, stats);
    finalize3_k<<<3, 256, 0, stream>>>(stats, g1, b1, g2, b2, g3, b3, ss);
    apply3_k<<<16384, 256, 0, stream>>>(hbuf,
                                        hbuf + (size_t)NP * CC,
                                        hbuf + (size_t)2 * NP * CC,
                                        ss, feat, out);
}